// Round 3
// baseline (193.527 us; speedup 1.0000x reference)
//
#include <hip/hip_runtime.h>

// GnnLayer: out[50000,64] = leaky_relu((h[idx]/dist).reshape(N,2048) @ W + bias)
// R3: MROWS=64 (grid 782, occupancy back), BK=256 staging w/ VGPR prefetch,
// add-swizzled sB (conflict-free writes AND reads), meta as 1 uint4/stage,
// fp32 h gathered direct from global with fused scale+bf16 pack (no h prepass).
// ws: [0,256KB) W^T bf16 [64][2048]

#define N_NODES 50000
#define KN      32
#define FIN     64
#define FOUT    64
#define KDIM    2048
#define MROWS   64
#define BK      256            // K elems per stage
#define NSTAGE  (KDIM / BK)    // 8
#define META_STRIDE 36         // words; 144 B row stride (16B-aligned, 2-way banks)

typedef __attribute__((ext_vector_type(4))) float f32x4;
typedef __attribute__((ext_vector_type(8))) short bf16x8;

static __device__ __forceinline__ unsigned short f2b(float f) {
    union { float f; unsigned int u; } v; v.f = f;
    unsigned int u = v.u;
    return (unsigned short)((u + 0x7fffu + ((u >> 16) & 1u)) >> 16);  // RNE
}

// pack 8 fp32*scl -> bf16x8 (round-half-up via +0x8000, perm high halves)
static __device__ __forceinline__ bf16x8 scalepack8(float4 a, float4 b, float scl) {
    union { bf16x8 h; unsigned int u[4]; } out;
    float p0 = a.x * scl, p1 = a.y * scl, p2 = a.z * scl, p3 = a.w * scl;
    float p4 = b.x * scl, p5 = b.y * scl, p6 = b.z * scl, p7 = b.w * scl;
    unsigned int u0 = __builtin_bit_cast(unsigned int, p0) + 0x8000u;
    unsigned int u1 = __builtin_bit_cast(unsigned int, p1) + 0x8000u;
    unsigned int u2 = __builtin_bit_cast(unsigned int, p2) + 0x8000u;
    unsigned int u3 = __builtin_bit_cast(unsigned int, p3) + 0x8000u;
    unsigned int u4 = __builtin_bit_cast(unsigned int, p4) + 0x8000u;
    unsigned int u5 = __builtin_bit_cast(unsigned int, p5) + 0x8000u;
    unsigned int u6 = __builtin_bit_cast(unsigned int, p6) + 0x8000u;
    unsigned int u7 = __builtin_bit_cast(unsigned int, p7) + 0x8000u;
    out.u[0] = __builtin_amdgcn_perm(u1, u0, 0x07060302u);
    out.u[1] = __builtin_amdgcn_perm(u3, u2, 0x07060302u);
    out.u[2] = __builtin_amdgcn_perm(u5, u4, 0x07060302u);
    out.u[3] = __builtin_amdgcn_perm(u7, u6, 0x07060302u);
    return out.h;
}

// W[2048][64] fp32 -> W^T[64][2048] bf16. 64 blocks x 256 threads.
__global__ void k_prep(const float* __restrict__ w, unsigned short* __restrict__ wt) {
    int t = blockIdx.x * 256 + threadIdx.x;   // 0..16383
    int n = t >> 8, kb = t & 255;
    unsigned short o[8];
#pragma unroll
    for (int j = 0; j < 8; ++j)
        o[j] = f2b(w[(kb * 8 + j) * FOUT + n]);
    *(bf16x8*)(wt + n * KDIM + kb * 8) = *(bf16x8*)o;
}

// swizzled physical 16B-chunk index within a sB row
static __device__ __forceinline__ int swz(int c, int row) {
    return (c & 24) | ((c + 2 * (c >> 3) + row) & 7);
}

__global__ __launch_bounds__(256, 3) void k_main(
        const float*          __restrict__ hf,   // fp32 h [N][64]
        const float*          __restrict__ pos,  // [N][3]
        const int*            __restrict__ nidx, // [N][32]
        const unsigned short* __restrict__ wt,   // bf16 W^T [64][2048]
        const float*          __restrict__ bias, // [64]
        float*                __restrict__ out)  // [N][64]
{
    __shared__ unsigned short sB[FOUT * BK];             // 32 KB, swizzled
    __shared__ unsigned int   s_meta[MROWS * META_STRIDE]; // 9.2 KB idx|bf16(scl)

    const int tid = threadIdx.x;
    const int m0  = blockIdx.x * MROWS;

    // Phase 0: pack (idx, bf16(1/dist)) per (row, kn). 2-way banks (free).
    for (int p = tid; p < MROWS * KN; p += 256) {
        int row = p >> 5, kn = p & 31;
        int node = m0 + row;
        unsigned int pack = 0;
        if (node < N_NODES) {
            int idx = nidx[node * KN + kn];
            float dx = pos[node * 3 + 0] - pos[idx * 3 + 0];
            float dy = pos[node * 3 + 1] - pos[idx * 3 + 1];
            float dz = pos[node * 3 + 2] - pos[idx * 3 + 2];
            float sq = dx * dx + dy * dy + dz * dz;
            float scl = (sq == 0.f) ? 2.0f : __builtin_amdgcn_rsqf(sq);
            pack = (unsigned int)idx | ((unsigned int)f2b(scl) << 16);
        }
        s_meta[row * META_STRIDE + kn] = pack;
    }

    const int wv = tid >> 6, lane = tid & 63;
    const int lm = lane & 15, q = lane >> 4;
    const int arow = wv * 16 + lm;             // this lane's A row (fixed)
    const int srow = tid >> 2, sq4 = tid & 3;  // staging: 4 threads/row

    f32x4 acc[4] = {};

    // prefetch B stage 0 into VGPRs (128-B contiguous per thread)
    const unsigned short* wrow = wt + srow * KDIM + sq4 * 64;
    bf16x8 pre[8];
#pragma unroll
    for (int r = 0; r < 8; ++r)
        pre[r] = *(const bf16x8*)(wrow + r * 8);

    for (int s = 0; s < NSTAGE; ++s) {
        __syncthreads();   // prev-stage readers done (covers s_meta at s=0)
        {
            unsigned short* sr = sB + srow * BK;
#pragma unroll
            for (int r = 0; r < 8; ++r)
                *(bf16x8*)(sr + swz(sq4 * 8 + r, srow) * 8) = pre[r];
        }
        __syncthreads();
        if (s + 1 < NSTAGE) {
#pragma unroll
            for (int r = 0; r < 8; ++r)
                pre[r] = *(const bf16x8*)(wrow + (s + 1) * BK + r * 8);
        }
        // this stage's 4 metas for my row: one 16-B LDS read
        unsigned int mv[4];
        *(uint4*)mv = *(const uint4*)(s_meta + arow * META_STRIDE + s * 4);

#pragma unroll
        for (int kk2 = 0; kk2 < BK / 32; ++kk2) {
            const unsigned int meta = mv[kk2 >> 1];
            const float scl = __builtin_bit_cast(float, meta & 0xffff0000u);
            const float* ap = hf + (meta & 0xffffu) * FIN + (kk2 & 1) * 32 + q * 8;
            float4 a0 = *(const float4*)ap;
            float4 a1 = *(const float4*)(ap + 4);
            bf16x8 a = scalepack8(a0, a1, scl);
#pragma unroll
            for (int t = 0; t < 4; ++t) {
                bf16x8 b = *(const bf16x8*)(sB + (t * 16 + lm) * BK
                                            + swz(kk2 * 4 + q, lm) * 8);
                acc[t] = __builtin_amdgcn_mfma_f32_16x16x32_bf16(a, b, acc[t], 0, 0, 0);
            }
        }
    }

    // Epilogue: bias + leaky_relu. C/D: col=lane&15, row=q*4+reg.
#pragma unroll
    for (int t = 0; t < 4; ++t) {
        int f = t * 16 + lm;
        float bs = bias[f];
#pragma unroll
        for (int r = 0; r < 4; ++r) {
            int node = m0 + wv * 16 + q * 4 + r;
            if (node < N_NODES) {
                float v = acc[t][r] + bs;
                out[node * FOUT + f] = v > 0.f ? v : 0.01f * v;
            }
        }
    }
}

extern "C" void kernel_launch(void* const* d_in, const int* in_sizes, int n_in,
                              void* d_out, int out_size, void* d_ws, size_t ws_size,
                              hipStream_t stream) {
    const float* h    = (const float*)d_in[0];
    const float* pos  = (const float*)d_in[1];
    const int*   nidx = (const int*)d_in[2];
    const float* w    = (const float*)d_in[3];
    const float* bias = (const float*)d_in[4];
    float* out = (float*)d_out;

    unsigned short* wt = (unsigned short*)d_ws;  // 256 KB

    k_prep<<<64, 256, 0, stream>>>(w, wt);
    k_main<<<(N_NODES + MROWS - 1) / MROWS, 256, 0, stream>>>(h, pos, nidx, wt, bias, out);
}

// Round 4
// 172.295 us; speedup vs baseline: 1.1232x; 1.1232x over previous
//
#include <hip/hip_runtime.h>

// GnnLayer: out[50000,64] = leaky_relu((h[idx]/dist).reshape(N,2048) @ W + bias)
// R4: bf16 h pre-pass restored (halves gather bytes, L2-resident) + A-gather
// software-pipelined one full BK=256 stage ahead in registers. Swizzled sB,
// uint4 meta, VGPR B-prefetch, grid 782 (occupancy-friendly).
// ws: [0,256KB) W^T bf16 [64][2048]; [256KB,+6.4MB) hb bf16 [50000][64]

#define N_NODES 50000
#define KN      32
#define FIN     64
#define FOUT    64
#define KDIM    2048
#define MROWS   64
#define BK      256            // K elems per stage
#define NSTAGE  (KDIM / BK)    // 8
#define META_STRIDE 36         // words; 144-B row stride, 16B-aligned

typedef __attribute__((ext_vector_type(4))) float f32x4;
typedef __attribute__((ext_vector_type(8))) short bf16x8;

static __device__ __forceinline__ unsigned short f2b(float f) {
    union { float f; unsigned int u; } v; v.f = f;
    unsigned int u = v.u;
    return (unsigned short)((u + 0x7fffu + ((u >> 16) & 1u)) >> 16);  // RNE
}

// scale 8 bf16 by fp32: unpack pairs, mul, round-half-up, perm-pack high halves
static __device__ __forceinline__ bf16x8 scale8(bf16x8 v, float scl) {
    union U { bf16x8 h; unsigned int u[4]; };
    U in, out; in.h = v;
#pragma unroll
    for (int i = 0; i < 4; ++i) {
        unsigned int p = in.u[i];
        float lo = __builtin_bit_cast(float, p << 16);
        float hi = __builtin_bit_cast(float, p & 0xffff0000u);
        unsigned int rlo = __builtin_bit_cast(unsigned int, lo * scl) + 0x8000u;
        unsigned int rhi = __builtin_bit_cast(unsigned int, hi * scl) + 0x8000u;
        out.u[i] = __builtin_amdgcn_perm(rhi, rlo, 0x07060302u);
    }
    return out.h;
}

#define HB_BLOCKS ((N_NODES * FIN / 4) / 256)  // 3125

// fused prep: h fp32 -> bf16 ; W[2048][64] -> W^T bf16 [64][2048]
__global__ void k_prep(const float* __restrict__ h, const float* __restrict__ w,
                       unsigned short* __restrict__ hb, unsigned short* __restrict__ wt) {
    int b = blockIdx.x, tid = threadIdx.x;
    if (b < HB_BLOCKS) {
        int i = b * 256 + tid;
        float4 v = ((const float4*)h)[i];
        ushort4 p;
        p.x = f2b(v.x); p.y = f2b(v.y); p.z = f2b(v.z); p.w = f2b(v.w);
        ((ushort4*)hb)[i] = p;
    } else {
        int t = (b - HB_BLOCKS) * 256 + tid;   // 0..16383
        int n = t >> 8, kb = t & 255;
        unsigned short o[8];
#pragma unroll
        for (int j = 0; j < 8; ++j)
            o[j] = f2b(w[(kb * 8 + j) * FOUT + n]);
        *(bf16x8*)(wt + n * KDIM + kb * 8) = *(bf16x8*)o;
    }
}

// swizzled physical 16B-chunk index within a sB row (keyed by row&7)
static __device__ __forceinline__ int swz(int c, int row) {
    return (c & 24) | ((c + 2 * (c >> 3) + row) & 7);
}

__global__ __launch_bounds__(256, 3) void k_main(
        const unsigned short* __restrict__ hb,   // bf16 h [N][64]
        const float*          __restrict__ pos,  // [N][3]
        const int*            __restrict__ nidx, // [N][32]
        const unsigned short* __restrict__ wt,   // bf16 W^T [64][2048]
        const float*          __restrict__ bias, // [64]
        float*                __restrict__ out)  // [N][64]
{
    __shared__ unsigned short sB[FOUT * BK];               // 32 KB, swizzled
    __shared__ unsigned int   s_meta[MROWS * META_STRIDE]; // 9.2 KB idx|bf16(scl)

    const int tid = threadIdx.x;
    const int m0  = blockIdx.x * MROWS;

    // Phase 0: pack (idx, bf16(1/dist)) per (row, kn).
    for (int p = tid; p < MROWS * KN; p += 256) {
        int row = p >> 5, kn = p & 31;
        int node = m0 + row;
        unsigned int pack = 0;
        if (node < N_NODES) {
            int idx = nidx[node * KN + kn];
            float dx = pos[node * 3 + 0] - pos[idx * 3 + 0];
            float dy = pos[node * 3 + 1] - pos[idx * 3 + 1];
            float dz = pos[node * 3 + 2] - pos[idx * 3 + 2];
            float sq = dx * dx + dy * dy + dz * dz;
            float scl = (sq == 0.f) ? 2.0f : __builtin_amdgcn_rsqf(sq);
            pack = (unsigned int)idx | ((unsigned int)f2b(scl) << 16);
        }
        s_meta[row * META_STRIDE + kn] = pack;
    }

    const int wv = tid >> 6, lane = tid & 63;
    const int lm = lane & 15, q = lane >> 4;
    const int arow = wv * 16 + lm;             // this lane's A row (fixed)
    const int srow = tid >> 2, sq4 = tid & 3;  // sB staging: 4 threads/row

    f32x4 acc[4] = {};

    // prefetch B stage 0 into VGPRs (128-B contiguous per thread, L2-hot)
    const unsigned short* wrow = wt + srow * KDIM + sq4 * 64;
    bf16x8 pre[8];
#pragma unroll
    for (int r = 0; r < 8; ++r)
        pre[r] = *(const bf16x8*)(wrow + r * 8);

    __syncthreads();   // s_meta valid

    // prefetch A stage 0 (raw bf16; scale applied at consume time)
    unsigned int mvC[4];
    *(uint4*)mvC = *(const uint4*)(s_meta + arow * META_STRIDE);
    bf16x8 aC[8];
#pragma unroll
    for (int kk2 = 0; kk2 < 8; ++kk2)
        aC[kk2] = *(const bf16x8*)(hb + (mvC[kk2 >> 1] & 0xffffu) * FIN
                                   + (kk2 & 1) * 32 + q * 8);

    for (int s = 0; s < NSTAGE; ++s) {
        if (s) __syncthreads();   // stage s-1 sB readers done
        {
            unsigned short* sr = sB + srow * BK;
#pragma unroll
            for (int r = 0; r < 8; ++r)
                *(bf16x8*)(sr + swz(sq4 * 8 + r, srow) * 8) = pre[r];
        }
        __syncthreads();

        // B prefetch for stage s+1
        if (s + 1 < NSTAGE) {
#pragma unroll
            for (int r = 0; r < 8; ++r)
                pre[r] = *(const bf16x8*)(wrow + (s + 1) * BK + r * 8);
        }
        // A prefetch for stage s+1 (in flight through this stage's MFMA loop)
        unsigned int mvN[4];
        bf16x8 aN[8];
        if (s + 1 < NSTAGE) {
            *(uint4*)mvN = *(const uint4*)(s_meta + arow * META_STRIDE + (s + 1) * 4);
#pragma unroll
            for (int kk2 = 0; kk2 < 8; ++kk2)
                aN[kk2] = *(const bf16x8*)(hb + (mvN[kk2 >> 1] & 0xffffu) * FIN
                                           + (kk2 & 1) * 32 + q * 8);
        }

        // consume stage s
#pragma unroll
        for (int kk2 = 0; kk2 < 8; ++kk2) {
            float scl = __builtin_bit_cast(float, mvC[kk2 >> 1] & 0xffff0000u);
            bf16x8 a = scale8(aC[kk2], scl);
#pragma unroll
            for (int t = 0; t < 4; ++t) {
                bf16x8 b = *(const bf16x8*)(sB + (t * 16 + lm) * BK
                                            + swz(kk2 * 4 + q, lm) * 8);
                acc[t] = __builtin_amdgcn_mfma_f32_16x16x32_bf16(a, b, acc[t], 0, 0, 0);
            }
        }

        if (s + 1 < NSTAGE) {
#pragma unroll
            for (int kk2 = 0; kk2 < 8; ++kk2) aC[kk2] = aN[kk2];
#pragma unroll
            for (int i = 0; i < 4; ++i) mvC[i] = mvN[i];
        }
    }

    // Epilogue: bias + leaky_relu. C/D: col=lane&15, row=q*4+reg.
#pragma unroll
    for (int t = 0; t < 4; ++t) {
        int f = t * 16 + lm;
        float bs = bias[f];
#pragma unroll
        for (int r = 0; r < 4; ++r) {
            int node = m0 + wv * 16 + q * 4 + r;
            if (node < N_NODES) {
                float v = acc[t][r] + bs;
                out[node * FOUT + f] = v > 0.f ? v : 0.01f * v;
            }
        }
    }
}

extern "C" void kernel_launch(void* const* d_in, const int* in_sizes, int n_in,
                              void* d_out, int out_size, void* d_ws, size_t ws_size,
                              hipStream_t stream) {
    const float* h    = (const float*)d_in[0];
    const float* pos  = (const float*)d_in[1];
    const int*   nidx = (const int*)d_in[2];
    const float* w    = (const float*)d_in[3];
    const float* bias = (const float*)d_in[4];
    float* out = (float*)d_out;

    unsigned short* wt = (unsigned short*)d_ws;                    // 256 KB
    unsigned short* hb = (unsigned short*)((char*)d_ws + 262144);  // 6.4 MB

    k_prep<<<HB_BLOCKS + 64, 256, 0, stream>>>(h, w, hb, wt);
    k_main<<<(N_NODES + MROWS - 1) / MROWS, 256, 0, stream>>>(hb, pos, nidx, wt, bias, out);
}